// Round 1
// 292.951 us; speedup vs baseline: 1.0036x; 1.0036x over previous
//
#include <hip/hip_runtime.h>
#include <math.h>

// ---------------------------------------------------------------------------
// R5 (fused, deferred-reduction):
//   Evidence: top-5 dispatches are all 784-MiB harness poison fills (~120 us
//   @ 6.85 TB/s); our kernels are each <119 us yet dur_us=294 -> >=2 fills are
//   inside the timed window. Controllable portion ~54 us vs a 33 us HBM floor
//   (X = 196 MiB read once).
//   R4's GEMV lost ~40% of BW because every loop iteration ended with a
//   48-shuffle butterfly + exec-masked store: ~600+ cycles with no loads in
//   flight, and the branch blocked cross-iteration load pipelining.
//   R5: one kernel. Each wave owns 8 consecutive samples. Main body is pure
//   loads+FMA (ping-pong buffers, 32 accumulators, no shuffles/branches).
//   A single exchange-halving reduction (32 shuffles total, vs 192) runs once
//   per wave, then lanes 0-7 run the quantum sim + MLP and write out[].
//   No LDS, no workspace, no second launch, no `pre` round-trip.
// ---------------------------------------------------------------------------

constexpr int ROW  = 784;   // floats per input row
constexpr int ROW4 = 196;   // float4 per input row

__device__ __forceinline__ void apply_rx(float (&sr)[16], float (&si)[16],
                                         int mask, float c, float s)
{
    #pragma unroll
    for (int i = 0; i < 16; i++) {
        if (!(i & mask)) {
            int j = i | mask;
            float x0 = sr[i], y0 = si[i], x1 = sr[j], y1 = si[j];
            sr[i] = fmaf(c, x0,  s * y1);   // Re(c*s0 - i*s*s1)
            si[i] = fmaf(c, y0, -s * x1);   // Im(c*s0 - i*s*s1)
            sr[j] = fmaf(c, x1,  s * y0);   // Re(-i*s*s0 + c*s1)
            si[j] = fmaf(c, y1, -s * x0);   // Im(-i*s*s0 + c*s1)
        }
    }
}

__device__ __forceinline__ void apply_cnot(float (&sr)[16], float (&si)[16],
                                           int cmask, int tmask)
{
    #pragma unroll
    for (int i = 0; i < 16; i++) {
        if ((i & cmask) && !(i & tmask)) {
            int j = i | tmask;
            float tr = sr[i]; sr[i] = sr[j]; sr[j] = tr;
            float ti = si[i]; si[i] = si[j]; si[j] = ti;
        }
    }
}

// ---- macros keep all array indexing compile-time (no scratch; rule #20) ----
#define FMA_ONE(xv, wrow, o0) \
    a[(o0)+0] = fmaf(xv, wrow.x, a[(o0)+0]); \
    a[(o0)+1] = fmaf(xv, wrow.y, a[(o0)+1]); \
    a[(o0)+2] = fmaf(xv, wrow.z, a[(o0)+2]); \
    a[(o0)+3] = fmaf(xv, wrow.w, a[(o0)+3]);

#define FMA_ROUND(xb, o0, o1) { \
    _Pragma("unroll") \
    for (int i = 0; i < 4; i++) { \
        FMA_ONE(xb[i].x,     w[i][0], o0) FMA_ONE(xb[4+i].x, w[i][0], o1) \
        FMA_ONE(xb[i].y,     w[i][1], o0) FMA_ONE(xb[4+i].y, w[i][1], o1) \
        FMA_ONE(xb[i].z,     w[i][2], o0) FMA_ONE(xb[4+i].z, w[i][2], o1) \
        FMA_ONE(xb[i].w,     w[i][3], o0) FMA_ONE(xb[4+i].w, w[i][3], o1) \
    } }

#define LOAD_ROUND(dst, sA, sB) { \
    const float4* p0_ = X4 + (size_t)(sA) * ROW4; \
    const float4* p1_ = X4 + (size_t)(sB) * ROW4; \
    dst[0] = p0_[lane];        dst[4] = p1_[lane]; \
    dst[1] = p0_[lane + 64];   dst[5] = p1_[lane + 64]; \
    dst[2] = p0_[lane + 128];  dst[6] = p1_[lane + 128]; \
    dst[3] = tail ? p0_[192 + lane] : zero4; \
    dst[7] = tail ? p1_[192 + lane] : zero4; }

__global__ __launch_bounds__(256) void fused_kernel(
    const float* __restrict__ X,    // [B,784]
    const float* __restrict__ W1,   // [784,4]
    const float* __restrict__ b1,   // [4]
    const float* __restrict__ qw,   // [2,4]
    const float* __restrict__ W2,   // [4,32]
    const float* __restrict__ b2,   // [32]
    const float* __restrict__ W3,   // [32,2]
    const float* __restrict__ b3,   // [2]
    float* __restrict__ out,        // [B,2]
    int B)
{
    const int lane = threadIdx.x & 63;
    const int wid  = (blockIdx.x * 256 + threadIdx.x) >> 6;
    const int nW   = (gridDim.x * 256) >> 6;
    const bool tail = (lane < 4);
    const int  jt   = 192 + (lane & 3);

    const float4* X4   = reinterpret_cast<const float4*>(X);
    const float4* W1f4 = reinterpret_cast<const float4*>(W1);

    // W1 rows in registers (64 VGPR), loaded once per wave, L2-resident.
    float4 w[4][4];
    #pragma unroll
    for (int i = 0; i < 4; i++) {
        const int j4 = (i < 3) ? (lane + (i << 6)) : jt;
        #pragma unroll
        for (int p = 0; p < 4; p++) w[i][p] = W1f4[4 * j4 + p];
    }

    // Exchange-halving reduction: lane L ends up holding the total for
    // logical index idx = 16*b5 + 8*b4 + 4*b3 + 2*b2 + 1*b1 (bits of L),
    // where idx = 4*t + k  (t = sample-in-wave 0..7, k = output column 0..3).
    const int idx = ((lane >> 5) & 1) * 16 + ((lane >> 4) & 1) * 8 +
                    ((lane >> 3) & 1) * 4  + ((lane >> 2) & 1) * 2 +
                    ((lane >> 1) & 1);
    const float bl = b1[idx & 3];

    const bool b5  = (lane & 32) != 0;
    const bool b4  = (lane & 16) != 0;
    const bool b3f = (lane & 8)  != 0;
    const bool b2f = (lane & 4)  != 0;
    const bool b1f = (lane & 2)  != 0;

    const float4 zero4 = make_float4(0.f, 0.f, 0.f, 0.f);
    const int sl = B - 1;

    for (int S = wid * 8; S < B; S += nW * 8) {
        // clamped sample rows (exact fit for B=65536; safe for ragged B)
        const int s0 = (S     < sl) ? S     : sl;
        const int s1 = (S + 1 < sl) ? S + 1 : sl;
        const int s2 = (S + 2 < sl) ? S + 2 : sl;
        const int s3 = (S + 3 < sl) ? S + 3 : sl;
        const int s4 = (S + 4 < sl) ? S + 4 : sl;
        const int s5 = (S + 5 < sl) ? S + 5 : sl;
        const int s6 = (S + 6 < sl) ? S + 6 : sl;
        const int s7 = (S + 7 < sl) ? S + 7 : sl;

        float a[32];
        #pragma unroll
        for (int i = 0; i < 32; i++) a[i] = 0.f;

        // Pure load+FMA pipeline: L0 L1 F0 L2 F1 L3 F2 F3 — loads always in
        // flight during FMA; no cross-lane ops, no branches, no stores.
        float4 xA[8], xB[8];
        LOAD_ROUND(xA, s0, s1)
        LOAD_ROUND(xB, s2, s3)
        FMA_ROUND(xA, 0, 4)
        LOAD_ROUND(xA, s4, s5)
        FMA_ROUND(xB, 8, 12)
        LOAD_ROUND(xB, s6, s7)
        FMA_ROUND(xA, 16, 20)
        FMA_ROUND(xB, 24, 28)

        // ---- one exchange-halving reduction for all 32 partials ----------
        float v16[16];
        #pragma unroll
        for (int i = 0; i < 16; i++) {
            float kv = b5 ? a[i + 16] : a[i];
            float sv = b5 ? a[i]      : a[i + 16];
            v16[i] = kv + __shfl_xor(sv, 32);
        }
        float v8a[8];
        #pragma unroll
        for (int i = 0; i < 8; i++) {
            float kv = b4 ? v16[i + 8] : v16[i];
            float sv = b4 ? v16[i]     : v16[i + 8];
            v8a[i] = kv + __shfl_xor(sv, 16);
        }
        float v4a[4];
        #pragma unroll
        for (int i = 0; i < 4; i++) {
            float kv = b3f ? v8a[i + 4] : v8a[i];
            float sv = b3f ? v8a[i]     : v8a[i + 4];
            v4a[i] = kv + __shfl_xor(sv, 8);
        }
        float v2a[2];
        #pragma unroll
        for (int i = 0; i < 2; i++) {
            float kv = b2f ? v4a[i + 2] : v4a[i];
            float sv = b2f ? v4a[i]     : v4a[i + 2];
            v2a[i] = kv + __shfl_xor(sv, 4);
        }
        float kv = b1f ? v2a[1] : v2a[0];
        float sv = b1f ? v2a[0] : v2a[1];
        float v1 = kv + __shfl_xor(sv, 2);
        v1 += __shfl_xor(v1, 1);

        // bias + relu -> this lane's pre[t][k]
        const float pre_val = fmaxf(v1 + bl, 0.f);

        // Gather: lane j (j<8) collects sample j's 4 angles. idx=4j+k lives
        // at lanes 8j+2k (bit0 duplicate). All lanes active for the shuffles.
        const float p0 = __shfl(pre_val, ((lane & 7) << 3) + 0);
        const float p1 = __shfl(pre_val, ((lane & 7) << 3) + 2);
        const float p2 = __shfl(pre_val, ((lane & 7) << 3) + 4);
        const float p3 = __shfl(pre_val, ((lane & 7) << 3) + 6);

        // ---- fused epilogue: quantum sim + MLP on lanes 0..7 -------------
        if (lane < 8 && S + lane < B) {
            const int s = S + lane;

            float sr[16], si[16];
            #pragma unroll
            for (int i = 0; i < 16; i++) { sr[i] = 0.f; si[i] = 0.f; }
            sr[0] = 1.f;

            {   // AngleEmbedding: RX(pre_q) on wire q (wire0 = MSB = mask 8)
                float c, sn;
                __sincosf(p0 * 0.5f, &sn, &c); apply_rx(sr, si, 8, c, sn);
                __sincosf(p1 * 0.5f, &sn, &c); apply_rx(sr, si, 4, c, sn);
                __sincosf(p2 * 0.5f, &sn, &c); apply_rx(sr, si, 2, c, sn);
                __sincosf(p3 * 0.5f, &sn, &c); apply_rx(sr, si, 1, c, sn);
            }

            #pragma unroll
            for (int l = 0; l < 2; l++) {
                #pragma unroll
                for (int q = 0; q < 4; q++) {
                    float c, sn;
                    __sincosf(qw[l * 4 + q] * 0.5f, &sn, &c);
                    apply_rx(sr, si, 8 >> q, c, sn);
                }
                apply_cnot(sr, si, 8, 4);
                apply_cnot(sr, si, 4, 2);
                apply_cnot(sr, si, 2, 1);
                apply_cnot(sr, si, 1, 8);
            }

            float z0 = 0.f, z1 = 0.f, z2 = 0.f, z3 = 0.f;
            #pragma unroll
            for (int i = 0; i < 16; i++) {
                float p = fmaf(sr[i], sr[i], si[i] * si[i]);
                z0 += (i & 8) ? -p : p;
                z1 += (i & 4) ? -p : p;
                z2 += (i & 2) ? -p : p;
                z3 += (i & 1) ? -p : p;
            }
            z0 = (z0 == z0) ? z0 : 0.f;
            z1 = (z1 == z1) ? z1 : 0.f;
            z2 = (z2 == z2) ? z2 : 0.f;
            z3 = (z3 == z3) ? z3 : 0.f;

            float l0 = b3[0], l1 = b3[1];
            #pragma unroll
            for (int k = 0; k < 32; k++) {
                float v = b2[k];
                v = fmaf(z0, W2[k],      v);
                v = fmaf(z1, W2[32 + k], v);
                v = fmaf(z2, W2[64 + k], v);
                v = fmaf(z3, W2[96 + k], v);
                v = fmaxf(v, 0.f);
                l0 = fmaf(v, W3[2 * k],     l0);
                l1 = fmaf(v, W3[2 * k + 1], l1);
            }

            float m  = fmaxf(l0, l1);
            float e0 = __expf(l0 - m), e1 = __expf(l1 - m);
            float inv = 1.f / (e0 + e1);
            reinterpret_cast<float2*>(out)[s] = make_float2(e0 * inv, e1 * inv);
        }
    }
}

// ---------------------------------------------------------------------------
extern "C" void kernel_launch(void* const* d_in, const int* in_sizes, int n_in,
                              void* d_out, int out_size, void* d_ws, size_t ws_size,
                              hipStream_t stream)
{
    const float* X  = (const float*)d_in[0];  // [B,28,28]
    const float* W1 = (const float*)d_in[1];  // [784,4]
    const float* b1 = (const float*)d_in[2];  // [4]
    const float* qw = (const float*)d_in[3];  // [2,4]
    const float* W2 = (const float*)d_in[4];  // [4,32]
    const float* b2 = (const float*)d_in[5];  // [32]
    const float* W3 = (const float*)d_in[6];  // [32,2]
    const float* b3 = (const float*)d_in[7];  // [2]

    const int B = in_sizes[0] / ROW;

    // 2048 blocks x 256 thr = 8192 waves x 8 samples = 65536: one pass/wave.
    fused_kernel<<<2048, 256, 0, stream>>>(X, W1, b1, qw, W2, b2, W3, b3,
                                           (float*)d_out, B);
}